// Round 5
// baseline (651.495 us; speedup 1.0000x reference)
//
#include <hip/hip_runtime.h>
#include <math.h>

#define N_NODES 20000
#define N_EDGESI 200000
#define E_TOT   220000
#define N_FEAT  2048
#define H1      512
#define H2      30

typedef __bf16 bf16x8 __attribute__((ext_vector_type(8)));
typedef float  floatx4 __attribute__((ext_vector_type(4)));

// ---- async global->LDS DMA (16B), counted-vmcnt barriers (T3/T4) -----------
__device__ __forceinline__ void gl16(const void* g, void* l) {
    __builtin_amdgcn_global_load_lds(
        (const __attribute__((address_space(1))) unsigned int*)g,
        (__attribute__((address_space(3))) unsigned int*)l, 16, 0, 0);
}
// wait until only the newest 4 vmem ops (this iter's 4 DMA loads) are
// outstanding -> previous tile fully landed; then raw barrier (no vmcnt(0)
// drain: the in-flight tile survives the barrier).
__device__ __forceinline__ void stage_barrier4() {
    asm volatile("s_waitcnt vmcnt(4) lgkmcnt(0)" ::: "memory");
    __builtin_amdgcn_s_barrier();
}
__device__ __forceinline__ void stage_barrier0() {
    asm volatile("s_waitcnt vmcnt(0) lgkmcnt(0)" ::: "memory");
    __builtin_amdgcn_s_barrier();
}

__device__ __forceinline__ unsigned short f2bf(float f) {   // RNE
    unsigned int u = __float_as_uint(f);
    unsigned int r = (u + 0x7FFF + ((u >> 16) & 1)) >> 16;
    return (unsigned short)r;
}
__device__ __forceinline__ unsigned int packtrunc(float a, float b) {
    return (__float_as_uint(a) >> 16) | (__float_as_uint(b) & 0xFFFF0000u);
}
__device__ __forceinline__ unsigned int packrne(float a, float b) {
    return (unsigned int)f2bf(a) | ((unsigned int)f2bf(b) << 16);
}
__device__ __forceinline__ bf16x8 u4_to_bf(uint4 u) {
    union { uint4 u; bf16x8 b; } cv; cv.u = u; return cv.b;
}

// ---- W1 conversion: w1bf[k][n] (straight) + w1tbf[n][k] (transposed) -------
__global__ __launch_bounds__(256) void cvtW1(const float* __restrict__ W1,
                                             unsigned short* __restrict__ w1bf,
                                             unsigned short* __restrict__ w1tbf) {
    __shared__ float tile[32][33];
    const int bk = blockIdx.y * 32, bn = blockIdx.x * 32;
    const int tc = threadIdx.x & 31, tr = threadIdx.x >> 5;  // 8 rows/pass
    for (int r = tr; r < 32; r += 8) {
        float v = W1[(size_t)(bk + r) * H1 + bn + tc];
        w1bf[(size_t)(bk + r) * H1 + bn + tc] = f2bf(v);
        tile[r][tc] = v;
    }
    __syncthreads();
    for (int r = tr; r < 32; r += 8) {
        w1tbf[(size_t)(bn + r) * N_FEAT + bk + tc] = f2bf(tile[tc][r]);
    }
}

// ---- GEMM1: xw1 = features @ W1 --------------------------------------------
// Triple-buffered LDS, global_load_lds DMA staging (no ds_write leg on the
// barrier chain), stage 2 tiles ahead, counted vmcnt(4) per iteration.
// LDS is XOR-swizzled with pre-swizzled GLOBAL source (both-sides rule):
//   A fp32 [64 rows][8x16B chunks]: phys_chunk = logical ^ (row&7)
//   B bf16 [128 rows][4x16B chunks]: phys_chunk = logical ^ ((row>>1)&3)
// -> every frag ds_read spreads 64 lanes uniformly over all 8 bank-granules
// (conflict-free). A packed fp32->bf16 on the read side (VALU is idle).
__global__ __launch_bounds__(256, 3) void gemm1_mfma(const float* __restrict__ A,          // [20000,2048] fp32
                                                     const unsigned short* __restrict__ Bt, // [512,2048] bf16
                                                     unsigned short* __restrict__ C,        // [20000,512] bf16
                                                     const float* __restrict__ atts,
                                                     const float* __restrict__ attd,
                                                     float* __restrict__ a1s,
                                                     float* __restrict__ a1d) {
    __shared__ float          Asb[3][64 * 32];    // 3 x 8KB (fp32)
    __shared__ unsigned short Bsb[3][128 * 32];   // 3 x 8KB (bf16)
    const int blk = blockIdx.x;
    const int xcd = blk & 7, rr = blk >> 3;
    const int ntile = rr & 3, group = rr >> 2;
    const int stripe = group * 8 + xcd;
    if (stripe >= 313) return;
    const int bm = stripe * 64, bn = ntile * 128;
    const int t = threadIdx.x;
    const int lane = t & 63, w = t >> 6;
    const int wm = w >> 1, wn = w & 1;          // wave: rows wm*32..+31, cols wn*64..+63
    const int ln = lane & 15, qd = lane >> 4;

    // ---- staging geometry (thread t handles chunks t and t+256) ----
    const int ci0 = t, ci1 = t + 256;
    // A: 64 rows x 8 chunks (fp32, 128B rows)
    const int ar0 = ci0 >> 3, ap0 = ci0 & 7;
    const int ar1 = ci1 >> 3, ap1 = ci1 & 7;
    int gra0 = bm + ar0; if (gra0 > N_NODES - 1) gra0 = N_NODES - 1;
    int gra1 = bm + ar1; if (gra1 > N_NODES - 1) gra1 = N_NODES - 1;
    const float* gA0 = A + (size_t)gra0 * N_FEAT + ((ap0 ^ (ar0 & 7)) << 2);
    const float* gA1 = A + (size_t)gra1 * N_FEAT + ((ap1 ^ (ar1 & 7)) << 2);
    const int ldsA0 = ci0 * 4, ldsA1 = ci1 * 4;      // float index
    // B: 128 rows x 4 chunks (bf16, 64B rows)
    const int br0 = ci0 >> 2, bp0 = ci0 & 3;
    const int br1 = ci1 >> 2, bp1 = ci1 & 3;
    const unsigned short* gB0 = Bt + (size_t)(bn + br0) * N_FEAT + ((bp0 ^ ((br0 >> 1) & 3)) << 3);
    const unsigned short* gB1 = Bt + (size_t)(bn + br1) * N_FEAT + ((bp1 ^ ((br1 >> 1) & 3)) << 3);
    const int ldsB0 = ci0 * 8, ldsB1 = ci1 * 8;      // short index

#define STAGE1(k0, Ab, Bb) do { \
        gl16(gA0 + (k0), (Ab) + ldsA0); \
        gl16(gA1 + (k0), (Ab) + ldsA1); \
        gl16(gB0 + (k0), (Bb) + ldsB0); \
        gl16(gB1 + (k0), (Bb) + ldsB1); \
    } while (0)

    // ---- read geometry (swizzled offsets, per-thread constants) ----
    int offA[2][2], offB[4];
#pragma unroll
    for (int i = 0; i < 2; i++) {
        int row = wm * 32 + i * 16 + ln;
#pragma unroll
        for (int h = 0; h < 2; h++)
            offA[i][h] = row * 32 + (((qd * 2 + h) ^ (row & 7)) << 2);
    }
#pragma unroll
    for (int j = 0; j < 4; j++) {
        int row = wn * 64 + j * 16 + ln;
        offB[j] = row * 32 + ((qd ^ ((row >> 1) & 3)) << 3);
    }

    floatx4 acc[2][4];
#pragma unroll
    for (int i = 0; i < 2; i++)
#pragma unroll
        for (int j = 0; j < 4; j++) acc[i][j] = (floatx4){0.f, 0.f, 0.f, 0.f};

#define COMPUTE1(Ab, Bb) do { \
        bf16x8 af_[2], bf_[4]; \
        _Pragma("unroll") for (int j = 0; j < 4; j++) \
            bf_[j] = *(const bf16x8*)(const void*)((Bb) + offB[j]); \
        _Pragma("unroll") for (int i = 0; i < 2; i++) { \
            float4 f0 = *(const float4*)((Ab) + offA[i][0]); \
            float4 f1 = *(const float4*)((Ab) + offA[i][1]); \
            uint4 pk; \
            pk.x = packtrunc(f0.x, f0.y); pk.y = packtrunc(f0.z, f0.w); \
            pk.z = packtrunc(f1.x, f1.y); pk.w = packtrunc(f1.z, f1.w); \
            af_[i] = u4_to_bf(pk); } \
        _Pragma("unroll") for (int i = 0; i < 2; i++) \
        _Pragma("unroll") for (int j = 0; j < 4; j++) \
            acc[i][j] = __builtin_amdgcn_mfma_f32_16x16x32_bf16(af_[i], bf_[j], acc[i][j], 0, 0, 0); \
    } while (0)

    // prologue: DMA tiles 0,1; wait tile0 (4 newer outstanding), barrier
    float *Ac = Asb[0], *An1 = Asb[1], *An2 = Asb[2];
    unsigned short *Bc = Bsb[0], *Bn1 = Bsb[1], *Bn2 = Bsb[2];
    STAGE1(0, Ac, Bc);
    STAGE1(32, An1, Bn1);
    stage_barrier4();

    for (int k = 0; k < 62; ++k) {
        STAGE1((k + 2) * 32, An2, Bn2);   // tile k+2 -> third buffer
        COMPUTE1(Ac, Bc);                 // tile k
        stage_barrier4();                 // tile k+1 landed; k+2 in flight
        float* ta = Ac; Ac = An1; An1 = An2; An2 = ta;
        unsigned short* tb = Bc; Bc = Bn1; Bn1 = Bn2; Bn2 = tb;
    }
    COMPUTE1(Ac, Bc);                     // k = 62
    stage_barrier0();                     // tile 63 landed
    { float* ta = Ac; Ac = An1; An1 = An2; An2 = ta;
      unsigned short* tb = Bc; Bc = Bn1; Bn1 = Bn2; Bn2 = tb; }
    COMPUTE1(Ac, Bc);                     // k = 63
#undef STAGE1
#undef COMPUTE1

    // C write
#pragma unroll
    for (int i = 0; i < 2; i++)
#pragma unroll
        for (int j = 0; j < 4; j++)
#pragma unroll
            for (int p = 0; p < 4; p++) {
                int m = bm + wm * 32 + i * 16 + qd * 4 + p;
                if (m < N_NODES) {
                    int n = bn + wn * 64 + j * 16 + ln;
                    C[(size_t)m * H1 + n] = f2bf(acc[i][j][p]);
                }
            }
    // fused a1s/a1d partial row-dots (this wave covers cols bn+wn*64 .. +63)
    float avs[4], avd[4];
#pragma unroll
    for (int j = 0; j < 4; j++) {
        int n = bn + wn * 64 + j * 16 + ln;
        avs[j] = atts[n];
        avd[j] = attd[n];
    }
#pragma unroll
    for (int i = 0; i < 2; i++)
#pragma unroll
        for (int p = 0; p < 4; p++) {
            float vs = 0.f, vd = 0.f;
#pragma unroll
            for (int j = 0; j < 4; j++) {
                vs += acc[i][j][p] * avs[j];
                vd += acc[i][j][p] * avd[j];
            }
#pragma unroll
            for (int msk = 1; msk < 16; msk <<= 1) {
                vs += __shfl_xor(vs, msk);
                vd += __shfl_xor(vd, msk);
            }
            if (ln == p) {
                int m = bm + wm * 32 + i * 16 + qd * 4 + p;
                if (m < N_NODES) {
                    unsafeAtomicAdd(a1s + m, vs);
                    unsafeAtomicAdd(a1d + m, vd);
                }
            }
        }
}

// ---- GEMM4: sum += (F - h3@W1^T)^2 ------------------------------------------
// Same DMA/triple-buffer/counted-vmcnt structure; A and B both bf16 (no pack).
// LDS [128 rows][4x16B chunks] swizzled phys = logical ^ ((row>>1)&3).
__global__ __launch_bounds__(256, 3) void gemm4_mse(const unsigned short* __restrict__ Ah, // h3bf [20000,512]
                                                    const unsigned short* __restrict__ B,  // w1bf [2048,512]
                                                    const float* __restrict__ F,           // [20000,2048] fp32
                                                    float* __restrict__ partial) {
    __shared__ unsigned short Asb[3][128 * 32];   // 3 x 8KB
    __shared__ unsigned short Bsb[3][128 * 32];   // 3 x 8KB
    __shared__ float red[256];
    const int blk = blockIdx.x;
    const int xcd = blk & 7, rr = blk >> 3;
    const int ntile = rr & 15, group = rr >> 4;
    const int stripe = group * 8 + xcd;
    if (stripe >= 157) return;
    const int bm = stripe * 128, bn = ntile * 128;
    const int t = threadIdx.x;
    const int lane = t & 63, w = t >> 6;
    const int wm = w >> 1, wn = w & 1;
    const int ln = lane & 15, qd = lane >> 4;

    // staging geometry: chunks t, t+256 over 128 rows x 4 chunks
    const int ci0 = t, ci1 = t + 256;
    const int r0c = ci0 >> 2, p0c = ci0 & 3;
    const int r1c = ci1 >> 2, p1c = ci1 & 3;
    int gra0 = bm + r0c; if (gra0 > N_NODES - 1) gra0 = N_NODES - 1;
    int gra1 = bm + r1c; if (gra1 > N_NODES - 1) gra1 = N_NODES - 1;
    const unsigned short* gA0 = Ah + (size_t)gra0 * H1 + ((p0c ^ ((r0c >> 1) & 3)) << 3);
    const unsigned short* gA1 = Ah + (size_t)gra1 * H1 + ((p1c ^ ((r1c >> 1) & 3)) << 3);
    const unsigned short* gB0 = B + (size_t)(bn + r0c) * H1 + ((p0c ^ ((r0c >> 1) & 3)) << 3);
    const unsigned short* gB1 = B + (size_t)(bn + r1c) * H1 + ((p1c ^ ((r1c >> 1) & 3)) << 3);
    const int lds0 = ci0 * 8, lds1 = ci1 * 8;    // short index

#define STAGE4(k0, Ab, Bb) do { \
        gl16(gA0 + (k0), (Ab) + lds0); \
        gl16(gA1 + (k0), (Ab) + lds1); \
        gl16(gB0 + (k0), (Bb) + lds0); \
        gl16(gB1 + (k0), (Bb) + lds1); \
    } while (0)

    int offA[4], offB[4];
#pragma unroll
    for (int i = 0; i < 4; i++) {
        int row = wm * 64 + i * 16 + ln;
        offA[i] = row * 32 + ((qd ^ ((row >> 1) & 3)) << 3);
    }
#pragma unroll
    for (int j = 0; j < 4; j++) {
        int row = wn * 64 + j * 16 + ln;
        offB[j] = row * 32 + ((qd ^ ((row >> 1) & 3)) << 3);
    }

    floatx4 acc[4][4];
#pragma unroll
    for (int i = 0; i < 4; i++)
#pragma unroll
        for (int j = 0; j < 4; j++) acc[i][j] = (floatx4){0.f, 0.f, 0.f, 0.f};

#define COMPUTE4(Ab, Bb) do { \
        bf16x8 af_[4], bf_[4]; \
        _Pragma("unroll") for (int i = 0; i < 4; i++) \
            af_[i] = *(const bf16x8*)(const void*)((Ab) + offA[i]); \
        _Pragma("unroll") for (int j = 0; j < 4; j++) \
            bf_[j] = *(const bf16x8*)(const void*)((Bb) + offB[j]); \
        _Pragma("unroll") for (int i = 0; i < 4; i++) \
        _Pragma("unroll") for (int j = 0; j < 4; j++) \
            acc[i][j] = __builtin_amdgcn_mfma_f32_16x16x32_bf16(af_[i], bf_[j], acc[i][j], 0, 0, 0); \
    } while (0)

    unsigned short *Ac = Asb[0], *An1 = Asb[1], *An2 = Asb[2];
    unsigned short *Bc = Bsb[0], *Bn1 = Bsb[1], *Bn2 = Bsb[2];
    STAGE4(0, Ac, Bc);
    STAGE4(32, An1, Bn1);
    stage_barrier4();

    for (int k = 0; k < 14; ++k) {
        STAGE4((k + 2) * 32, An2, Bn2);
        COMPUTE4(Ac, Bc);
        stage_barrier4();
        unsigned short* ta = Ac; Ac = An1; An1 = An2; An2 = ta;
        unsigned short* tb = Bc; Bc = Bn1; Bn1 = Bn2; Bn2 = tb;
    }
    COMPUTE4(Ac, Bc);                     // k = 14
    stage_barrier0();
    { unsigned short* ta = Ac; Ac = An1; An1 = An2; An2 = ta;
      unsigned short* tb = Bc; Bc = Bn1; Bn1 = Bn2; Bn2 = tb; }
    COMPUTE4(Ac, Bc);                     // k = 15
#undef STAGE4
#undef COMPUTE4

    float sum = 0.f;
#pragma unroll
    for (int i = 0; i < 4; i++)
#pragma unroll
        for (int j = 0; j < 4; j++)
#pragma unroll
            for (int p = 0; p < 4; p++) {
                int m = bm + wm * 64 + i * 16 + qd * 4 + p;
                if (m < N_NODES) {
                    int n = bn + wn * 64 + j * 16 + ln;
                    float fv = F[(size_t)m * N_FEAT + n];
                    float d = fv - acc[i][j][p];
                    sum += d * d;
                }
            }
    red[t] = sum;
    __syncthreads();
    for (int off = 128; off; off >>= 1) {
        if (t < off) red[t] += red[t + off];
        __syncthreads();
    }
    if (t == 0) unsafeAtomicAdd(partial, red[0]);
}

// ---- edge pass --------------------------------------------------------------
__global__ void edge_att(const int* __restrict__ ei,
                         const float* __restrict__ a1s,
                         const float* __restrict__ a1d,
                         float* __restrict__ ebuf,
                         float* __restrict__ den,
                         int* __restrict__ deg) {
    int e = blockIdx.x * blockDim.x + threadIdx.x;
    if (e >= E_TOT) return;
    int s, d;
    if (e < N_EDGESI) { s = ei[e]; d = ei[N_EDGESI + e]; }
    else { s = e - N_EDGESI; d = s; }
    float x = a1s[s] + a1d[d];
    float sig = 1.f / (1.f + __expf(-x));
    float ex = __expf(sig);
    ebuf[e] = ex;
    unsafeAtomicAdd(&den[d], ex);
    atomicAdd(&deg[d], 1);
}

// ---- exclusive prefix sum over deg -> off (wave-shuffle scan) ---------------
__global__ __launch_bounds__(1024) void scan_k(const int* __restrict__ deg,
                                               int* __restrict__ off) {
    __shared__ int wsum[16];
    __shared__ int carry_s;
    const int lane = threadIdx.x & 63, wid = threadIdx.x >> 6;
    if (threadIdx.x == 0) carry_s = 0;
    __syncthreads();
    for (int base = 0; base < N_NODES; base += 1024) {
        int i = base + threadIdx.x;
        int v = (i < N_NODES) ? deg[i] : 0;
        int x = v;
#pragma unroll
        for (int s = 1; s < 64; s <<= 1) {
            int tt = __shfl_up(x, s);
            if (lane >= s) x += tt;
        }
        if (lane == 63) wsum[wid] = x;
        __syncthreads();
        if (wid == 0 && lane < 16) {
            int wv = wsum[lane];
#pragma unroll
            for (int s = 1; s < 16; s <<= 1) {
                int tt = __shfl_up(wv, s);
                if (lane >= s) wv += tt;
            }
            wsum[lane] = wv;
        }
        __syncthreads();
        int wbase = (wid == 0) ? 0 : wsum[wid - 1];
        int c = carry_s;
        int incl = x + wbase + c;
        if (i < N_NODES) off[i] = incl - v;
        __syncthreads();
        if (threadIdx.x == 0) carry_s = c + wsum[15];
        __syncthreads();
    }
}

// ---- bucket edges into CSR slots -------------------------------------------
__global__ void bucket_k(const int* __restrict__ ei,
                         const float* __restrict__ ebuf,
                         const float* __restrict__ den,
                         int* __restrict__ cursor,
                         int* __restrict__ csr_src,
                         float* __restrict__ csr_coef) {
    int e = blockIdx.x * blockDim.x + threadIdx.x;
    if (e >= E_TOT) return;
    int s, d;
    if (e < N_EDGESI) { s = ei[e]; d = ei[N_EDGESI + e]; }
    else { s = e - N_EDGESI; d = s; }
    int pos = atomicAdd(&cursor[d], 1);
    csr_src[pos] = s;
    csr_coef[pos] = ebuf[e] / den[d];
}

// ---- gather (bf16): Y[d] = elu(sum coef * X[src]), unroll-2 dual acc --------
__global__ __launch_bounds__(256) void gather_elu_bf(const int* __restrict__ off,
                                                     const int* __restrict__ csr_src,
                                                     const float* __restrict__ csr_coef,
                                                     const unsigned short* __restrict__ X,
                                                     unsigned short* __restrict__ Y) {
    int d = blockIdx.x * 4 + (threadIdx.x >> 6);
    int lane = threadIdx.x & 63;
    if (d >= N_NODES) return;
    int beg = off[d];
    int end = (d == N_NODES - 1) ? E_TOT : off[d + 1];
    float a[8] = {0.f, 0.f, 0.f, 0.f, 0.f, 0.f, 0.f, 0.f};
    float b[8] = {0.f, 0.f, 0.f, 0.f, 0.f, 0.f, 0.f, 0.f};
    int j = beg;
    for (; j + 1 < end; j += 2) {
        int s0 = csr_src[j], s1 = csr_src[j + 1];
        float c0 = csr_coef[j], c1 = csr_coef[j + 1];
        uint4 raw0 = *(const uint4*)(X + (size_t)s0 * H1 + lane * 8);
        uint4 raw1 = *(const uint4*)(X + (size_t)s1 * H1 + lane * 8);
        a[0] += __uint_as_float(raw0.x << 16) * c0;
        a[1] += __uint_as_float(raw0.x & 0xFFFF0000u) * c0;
        a[2] += __uint_as_float(raw0.y << 16) * c0;
        a[3] += __uint_as_float(raw0.y & 0xFFFF0000u) * c0;
        a[4] += __uint_as_float(raw0.z << 16) * c0;
        a[5] += __uint_as_float(raw0.z & 0xFFFF0000u) * c0;
        a[6] += __uint_as_float(raw0.w << 16) * c0;
        a[7] += __uint_as_float(raw0.w & 0xFFFF0000u) * c0;
        b[0] += __uint_as_float(raw1.x << 16) * c1;
        b[1] += __uint_as_float(raw1.x & 0xFFFF0000u) * c1;
        b[2] += __uint_as_float(raw1.y << 16) * c1;
        b[3] += __uint_as_float(raw1.y & 0xFFFF0000u) * c1;
        b[4] += __uint_as_float(raw1.z << 16) * c1;
        b[5] += __uint_as_float(raw1.z & 0xFFFF0000u) * c1;
        b[6] += __uint_as_float(raw1.w << 16) * c1;
        b[7] += __uint_as_float(raw1.w & 0xFFFF0000u) * c1;
    }
    if (j < end) {
        int s0 = csr_src[j];
        float c0 = csr_coef[j];
        uint4 raw0 = *(const uint4*)(X + (size_t)s0 * H1 + lane * 8);
        a[0] += __uint_as_float(raw0.x << 16) * c0;
        a[1] += __uint_as_float(raw0.x & 0xFFFF0000u) * c0;
        a[2] += __uint_as_float(raw0.y << 16) * c0;
        a[3] += __uint_as_float(raw0.y & 0xFFFF0000u) * c0;
        a[4] += __uint_as_float(raw0.z << 16) * c0;
        a[5] += __uint_as_float(raw0.z & 0xFFFF0000u) * c0;
        a[6] += __uint_as_float(raw0.w << 16) * c0;
        a[7] += __uint_as_float(raw0.w & 0xFFFF0000u) * c0;
    }
#pragma unroll
    for (int e = 0; e < 8; e++) {
        float v = a[e] + b[e];
        a[e] = v > 0.f ? v : __expf(v) - 1.f;
    }
    uint4 o;
    o.x = packrne(a[0], a[1]);
    o.y = packrne(a[2], a[3]);
    o.z = packrne(a[4], a[5]);
    o.w = packrne(a[6], a[7]);
    *(uint4*)(Y + (size_t)d * H1 + lane * 8) = o;
}

// ---- h2 = normalize_rows(h1 @ W2), h1 in bf16 -------------------------------
__global__ __launch_bounds__(256) void gemm2_norm_bf(const unsigned short* __restrict__ H1b,
                                                     const float* __restrict__ W2,
                                                     float* __restrict__ h2n) {
    __shared__ float hs[8 * 516];
    const int n0 = blockIdx.x * 8;
    const int tid = threadIdx.x;
    for (int idx = tid; idx < 512; idx += 256) {
        int r = idx >> 6, c = (idx & 63) * 8;
        uint4 raw = *(const uint4*)(H1b + (size_t)(n0 + r) * H1 + c);
        float* hp = hs + r * 516 + c;
        hp[0] = __uint_as_float(raw.x << 16);
        hp[1] = __uint_as_float(raw.x & 0xFFFF0000u);
        hp[2] = __uint_as_float(raw.y << 16);
        hp[3] = __uint_as_float(raw.y & 0xFFFF0000u);
        hp[4] = __uint_as_float(raw.z << 16);
        hp[5] = __uint_as_float(raw.z & 0xFFFF0000u);
        hp[6] = __uint_as_float(raw.w << 16);
        hp[7] = __uint_as_float(raw.w & 0xFFFF0000u);
    }
    __syncthreads();
    const int sub = tid >> 5, j = tid & 31;
    float a0 = 0.f, a1 = 0.f, a2 = 0.f, a3 = 0.f;
    if (j < H2) {
        const float* hr = hs + sub * 516;
        for (int k = 0; k < H1; k += 4) {
            a0 += hr[k] * W2[k * H2 + j];
            a1 += hr[k + 1] * W2[(k + 1) * H2 + j];
            a2 += hr[k + 2] * W2[(k + 2) * H2 + j];
            a3 += hr[k + 3] * W2[(k + 3) * H2 + j];
        }
    }
    float acc = (a0 + a1) + (a2 + a3);
    float sq = acc * acc;
    for (int m = 16; m; m >>= 1) sq += __shfl_xor(sq, m, 32);
    float inv = 1.f / fmaxf(sqrtf(sq), 1e-12f);
    if (j < H2) h2n[(size_t)(n0 + sub) * H2 + j] = acc * inv;
}

// ---- xw3 = h2n @ W2^T -> bf16 (W2 rows in registers, h2n scalar-broadcast) --
#define G3_CHUNK 40
__global__ __launch_bounds__(256) void gemm3_k(const float* __restrict__ h2n,
                                               const float* __restrict__ W2,
                                               unsigned short* __restrict__ xw3) {
    const int t = threadIdx.x;
    const int h0 = t << 1;             // columns h0, h0+1 of [0,512)
    float w0[H2], w1[H2];
#pragma unroll
    for (int k = 0; k < H2; k++) {
        w0[k] = W2[(size_t)h0 * H2 + k];
        w1[k] = W2[(size_t)h0 * H2 + H2 + k];
    }
    const int n0 = blockIdx.x * G3_CHUNK;
    const int nend = (n0 + G3_CHUNK < N_NODES) ? n0 + G3_CHUNK : N_NODES;
    for (int n = n0; n < nend; n++) {
        const float* hr = h2n + (size_t)n * H2;
        float a0 = 0.f, a1 = 0.f;
#pragma unroll
        for (int k = 0; k < H2; k++) {
            float hv = hr[k];
            a0 += hv * w0[k];
            a1 += hv * w1[k];
        }
        *(unsigned int*)(xw3 + (size_t)n * H1 + h0) = packrne(a0, a1);
    }
}

__global__ void finalize_k(const float* __restrict__ partial, float* __restrict__ out) {
    out[0] = partial[0] * (1.f / ((float)N_NODES * (float)N_FEAT));
}

extern "C" void kernel_launch(void* const* d_in, const int* in_sizes, int n_in,
                              void* d_out, int out_size, void* d_ws, size_t ws_size,
                              hipStream_t stream) {
    const float* features = (const float*)d_in[0];
    const int*   ei       = (const int*)d_in[1];
    const float* W1       = (const float*)d_in[2];
    const float* atts     = (const float*)d_in[3];
    const float* attd     = (const float*)d_in[4];
    const float* W2       = (const float*)d_in[5];
    float* out = (float*)d_out;

    char* ws = (char*)d_ws;
    unsigned short* xw1bf = (unsigned short*)(ws);              // 20,480,000 B (also xw3bf)
    unsigned short* h3bf  = (unsigned short*)(ws + 20480000);   // 20,480,000 B
    unsigned short* h1bf  = (unsigned short*)(ws + 40960000);   // 20,480,000 B
    unsigned short* w1bf  = (unsigned short*)(ws + 61440000);   //  2,097,152 B
    unsigned short* w1tbf = (unsigned short*)(ws + 63537152);   //  2,097,152 B
    float* h2n      = (float*)(ws + 65634304);                  //  2,400,000 B
    // zero region (single memset): a1s,a1d,den,deg,partial
    float* a1s      = (float*)(ws + 68034304);                  // 80,000
    float* a1d      = (float*)(ws + 68114304);                  // 80,000
    float* den      = (float*)(ws + 68194304);                  // 80,000
    int*   deg      = (int*)  (ws + 68274304);                  // 80,000
    float* partial  = (float*)(ws + 68354304);                  // 16
    float* ebuf     = (float*)(ws + 68354320);                  // 880,000
    int*   off      = (int*)  (ws + 69234320);
    int*   cursor   = (int*)  (ws + 69314320);
    int*   csr_src  = (int*)  (ws + 69394320);                  // 880,000
    float* csr_coef = (float*)(ws + 70274320);                  // 880,000

    hipMemsetAsync(a1s, 0, 320016, stream);  // a1s,a1d,den,deg,partial

    // 0) W1 -> bf16 (straight + transposed)
    cvtW1<<<dim3(16, 64), 256, 0, stream>>>(W1, w1bf, w1tbf);

    // 1) xw1 = features @ W1 (DMA-staged MFMA, triple-buf, counted vmcnt)
    gemm1_mfma<<<1280, 256, 0, stream>>>(features, w1tbf, xw1bf, atts, attd, a1s, a1d);

    // 2) edge attention numerators + denominators + degree counts
    edge_att<<<(E_TOT + 255) / 256, 256, 0, stream>>>(ei, a1s, a1d, ebuf, den, deg);

    // 3) CSR build
    scan_k<<<1, 1024, 0, stream>>>(deg, off);
    hipMemcpyAsync(cursor, off, 20000 * 4, hipMemcpyDeviceToDevice, stream);
    bucket_k<<<(E_TOT + 255) / 256, 256, 0, stream>>>(ei, ebuf, den, cursor, csr_src, csr_coef);

    // 4) h1 = elu(gather(xw1))
    gather_elu_bf<<<N_NODES / 4, 256, 0, stream>>>(off, csr_src, csr_coef, xw1bf, h1bf);

    // 5) h2n = normalize_rows(h1 @ W2)
    gemm2_norm_bf<<<N_NODES / 8, 256, 0, stream>>>(h1bf, W2, h2n);

    // 6) xw3 = h2n @ W2^T (bf16 out, reuses xw1bf buffer)
    gemm3_k<<<(N_NODES + G3_CHUNK - 1) / G3_CHUNK, 256, 0, stream>>>(h2n, W2, xw1bf);

    // 7) h3 = elu(gather(xw3))
    gather_elu_bf<<<N_NODES / 4, 256, 0, stream>>>(off, csr_src, csr_coef, xw1bf, h3bf);

    // 8) fused h4 = h3 @ W1^T with MSE reduction (DMA-staged MFMA)
    gemm4_mse<<<2560, 256, 0, stream>>>(h3bf, w1bf, features, partial);

    // 9) finalize
    finalize_k<<<1, 1, 0, stream>>>(partial, out);
}